// Round 5
// baseline (902.523 us; speedup 1.0000x reference)
//
#include <hip/hip_runtime.h>
#include <hip/hip_bf16.h>

#define T_ 2048
#define D_ 2560
#define H_ 8
#define KV_ 4
#define HD_ 256
#define S_ 8192
#define PREV_ 4096
#define SEFF_ 6144
#define NT_ 192          // SEFF/32 key tiles
#define NS_ 2            // key-dim splits
#define TPS_ 96          // tiles per split (uniform absolute ranges)
#define CHT_ 8           // tiles per pacing chunk (live footprint 4g*256KB*2 = 2MB)
#define SCALE_ 0.0625f
#define LOG2E_ 1.44269504088896f

typedef __attribute__((ext_vector_type(8))) short short8;
typedef __attribute__((ext_vector_type(4))) float floatx4;

__device__ inline short8 ld8(const __hip_bfloat16* p) { return *(const short8*)p; }
__device__ inline short8 ld8(const float* p) {
    float4 a = *(const float4*)p;
    float4 b = *(const float4*)(p + 4);
    union { short8 s; __hip_bfloat16 h[8]; } u;
    u.h[0] = __hip_bfloat16(a.x); u.h[1] = __hip_bfloat16(a.y);
    u.h[2] = __hip_bfloat16(a.z); u.h[3] = __hip_bfloat16(a.w);
    u.h[4] = __hip_bfloat16(b.x); u.h[5] = __hip_bfloat16(b.y);
    u.h[6] = __hip_bfloat16(b.z); u.h[7] = __hip_bfloat16(b.w);
    return u.s;
}

__device__ inline short bfbits(float x) {
    __hip_bfloat16 h(x);
    short s;
    __builtin_memcpy(&s, &h, 2);
    return s;
}

__device__ inline float b2f(short u) {
    unsigned int x = ((unsigned int)(unsigned short)u) << 16;
    float f; __builtin_memcpy(&f, &x, 4); return f;
}

// async global -> LDS, 16B per lane, dest = wave-uniform base + lane*16
__device__ __forceinline__ void gld_lds(const short* g, short* l) {
    __builtin_amdgcn_global_load_lds(
        (const __attribute__((address_space(1))) unsigned int*)(const void*)g,
        (__attribute__((address_space(3))) unsigned int*)(void*)l,
        16, 0, 0);
}

// Packed K/V tile layouts (16B chunk slot within a 32-key tile) — the exact
// layouts attn's MFMA fragment reads use; producers bake them into global.
__device__ __forceinline__ int kslot(int row, int c) {   // row 0..31 (key), c 0..31 (16B chunk of 256-dim)
    int kk = c >> 2, qd = c & 3, hf = row >> 4, lrr = row & 15;
    return (kk * 2 + hf) * 64 + ((qd * 16 + lrr) ^ kk);
}
__device__ __forceinline__ int vslot(int d, int c) {     // d 0..255 (dim), c 0..3 (16B chunk of 32 keys)
    int ni = d >> 4, lrr = d & 15;
    return ni * 64 + ((c * 16 + lrr) ^ (ni & 7));
}

// ---------------- fused QKV GEMM: 128x128 tiles over N=4096 (Wq|Wk|Wv)
__global__ __launch_bounds__(256) void gemm_qkv(const float* __restrict__ A,   // x [2048][2560]
                                                const float* __restrict__ Wq,
                                                const float* __restrict__ Wk,
                                                const float* __restrict__ Wv,
                                                float* __restrict__ qo,        // [2048][2048]
                                                float* __restrict__ ko,        // [2048][1024]
                                                float* __restrict__ vo) {      // [2048][1024]
    __shared__ __align__(16) __hip_bfloat16 As[128 * 40];
    __shared__ __align__(16) __hip_bfloat16 Bs[128 * 40];
    const int K = D_;
    const int tid = threadIdx.x;
    const int bm = (int)blockIdx.y * 128, bn = (int)blockIdx.x * 128;
    const int w = tid >> 6, lane = tid & 63, quad = lane >> 4, lr = lane & 15;
    const int wm = (w >> 1) * 64, wn = (w & 1) * 64;
    floatx4 acc[4][4] = {};
    const int row = tid >> 2;
    const int col = (tid & 3) * 8;

    const float* Bp; float* Co; int nb, ldo;
    if (bn < 2048)      { Bp = Wq + (size_t)bn * K;          Co = qo; nb = bn;        ldo = 2048; }
    else if (bn < 3072) { Bp = Wk + (size_t)(bn - 2048) * K; Co = ko; nb = bn - 2048; ldo = 1024; }
    else                { Bp = Wv + (size_t)(bn - 3072) * K; Co = vo; nb = bn - 3072; ldo = 1024; }

    for (int k0 = 0; k0 < K; k0 += 32) {
        __syncthreads();
        for (int p = 0; p < 2; ++p) {
            int r = row + p * 64;
            *(short8*)(&As[r * 40 + col]) = ld8(&A[(size_t)(bm + r) * K + k0 + col]);
            *(short8*)(&Bs[r * 40 + col]) = ld8(&Bp[(size_t)r * K + k0 + col]);
        }
        __syncthreads();
        short8 a[4], b[4];
        for (int mi = 0; mi < 4; ++mi)
            a[mi] = *(const short8*)(&As[(wm + mi * 16 + lr) * 40 + quad * 8]);
        for (int ni = 0; ni < 4; ++ni)
            b[ni] = *(const short8*)(&Bs[(wn + ni * 16 + lr) * 40 + quad * 8]);
        for (int mi = 0; mi < 4; ++mi)
            for (int ni = 0; ni < 4; ++ni)
                acc[mi][ni] = __builtin_amdgcn_mfma_f32_16x16x32_bf16(a[mi], b[ni], acc[mi][ni], 0, 0, 0);
    }
    for (int mi = 0; mi < 4; ++mi)
        for (int ni = 0; ni < 4; ++ni)
            for (int r = 0; r < 4; ++r) {
                int m = bm + wm + mi * 16 + quad * 4 + r;
                int n = nb + wn + ni * 16 + lr;
                Co[(size_t)m * ldo + n] = acc[mi][ni][r];
            }
}

// ---------------- Wo GEMM: 64(M)x128(N) tiles; A=ctx bf16, B=Wo fp32, C=out fp32
__global__ __launch_bounds__(256) void gemm_wo(const __hip_bfloat16* __restrict__ A,  // [2048][2048]
                                               const float* __restrict__ Bm,          // [2560][2048]
                                               float* __restrict__ C) {               // [2048][2560]
    __shared__ __align__(16) __hip_bfloat16 As[64 * 40];
    __shared__ __align__(16) __hip_bfloat16 Bs[128 * 40];
    const int K = 2048, N = D_;
    const int tid = threadIdx.x;
    const int bm = (int)blockIdx.y * 64, bn = (int)blockIdx.x * 128;
    const int w = tid >> 6, lane = tid & 63, quad = lane >> 4, lr = lane & 15;
    const int wn = w * 32;
    floatx4 acc[4][2] = {};
    const int row = tid >> 2;
    const int col = (tid & 3) * 8;

    for (int k0 = 0; k0 < K; k0 += 32) {
        __syncthreads();
        *(short8*)(&As[row * 40 + col]) = ld8(&A[(size_t)(bm + row) * K + k0 + col]);
        for (int p = 0; p < 2; ++p) {
            int r = row + p * 64;
            *(short8*)(&Bs[r * 40 + col]) = ld8(&Bm[(size_t)(bn + r) * K + k0 + col]);
        }
        __syncthreads();
        short8 a[4], b[2];
        for (int mi = 0; mi < 4; ++mi)
            a[mi] = *(const short8*)(&As[(mi * 16 + lr) * 40 + quad * 8]);
        for (int ni = 0; ni < 2; ++ni)
            b[ni] = *(const short8*)(&Bs[(wn + ni * 16 + lr) * 40 + quad * 8]);
        for (int mi = 0; mi < 4; ++mi)
            for (int ni = 0; ni < 2; ++ni)
                acc[mi][ni] = __builtin_amdgcn_mfma_f32_16x16x32_bf16(a[mi], b[ni], acc[mi][ni], 0, 0, 0);
    }
    for (int mi = 0; mi < 4; ++mi)
        for (int ni = 0; ni < 2; ++ni)
            for (int r = 0; r < 4; ++r) {
                int m = bm + mi * 16 + quad * 4 + r;
                int n = bn + wn + ni * 16 + lr;
                C[(size_t)m * N + n] = acc[mi][ni][r];
            }
}

// ---------------- RMSNorm + RoPE (fp32) for Q, output bf16 [head][t][256]
__global__ __launch_bounds__(256) void norm_rope_q(const float* __restrict__ src,
                                                   const float* __restrict__ scale,
                                                   const float* __restrict__ cosd,
                                                   const float* __restrict__ sind,
                                                   __hip_bfloat16* __restrict__ dst) {
    const int rowid = blockIdx.x;
    const int t = rowid / H_, hh = rowid % H_;
    const int d = threadIdx.x;
    __shared__ float ybuf[256];
    __shared__ float wsum[4];
    float x = src[(size_t)t * (H_ * 256) + hh * 256 + d];
    float ss = x * x;
    for (int m = 1; m < 64; m <<= 1) ss += __shfl_xor(ss, m);
    if ((d & 63) == 0) wsum[d >> 6] = ss;
    __syncthreads();
    float tot = wsum[0] + wsum[1] + wsum[2] + wsum[3];
    float inv = rsqrtf(tot * (1.0f / 256.0f) + 1e-6f);
    float y = x * inv * (1.0f + scale[d]);
    ybuf[d] = y;
    __syncthreads();
    float rot = (d < 128) ? -ybuf[d + 128] : ybuf[d - 128];
    float cv = cosd[(size_t)t * 256 + d];
    float sv = sind[(size_t)t * 256 + d];
    float out = y * cv + rot * sv;
    dst[((size_t)hh * T_ + t) * 256 + d] = __hip_bfloat16(out);
}

// ---------------- RMSNorm + RoPE for new K rows -> packed Kp layout
__global__ __launch_bounds__(256) void norm_rope_k(const float* __restrict__ src,
                                                   const float* __restrict__ scale,
                                                   const float* __restrict__ cosd,
                                                   const float* __restrict__ sind,
                                                   short* __restrict__ Kp) {
    const int rowid = blockIdx.x;
    const int t = rowid / KV_, g = rowid % KV_;
    const int d = threadIdx.x;
    __shared__ float ybuf[256];
    __shared__ float wsum[4];
    float x = src[(size_t)t * (KV_ * 256) + g * 256 + d];
    float ss = x * x;
    for (int m = 1; m < 64; m <<= 1) ss += __shfl_xor(ss, m);
    if ((d & 63) == 0) wsum[d >> 6] = ss;
    __syncthreads();
    float tot = wsum[0] + wsum[1] + wsum[2] + wsum[3];
    float inv = rsqrtf(tot * (1.0f / 256.0f) + 1e-6f);
    float y = x * inv * (1.0f + scale[d]);
    ybuf[d] = y;
    __syncthreads();
    float rot = (d < 128) ? -ybuf[d + 128] : ybuf[d - 128];
    float cv = cosd[(size_t)t * 256 + d];
    float sv = sind[(size_t)t * 256 + d];
    float out = y * cv + rot * sv;
    const int s = t + PREV_;
    const int tile = s >> 5, row = s & 31;
    Kp[((size_t)(g * NT_ + tile) * 1024 + kslot(row, d >> 3)) * 8 + (d & 7)] = bfbits(out);
}

// ---------------- old K cache (fp32) -> packed Kp[g][tile][1024 chunks]
__global__ __launch_bounds__(256) void merge_k(const float* __restrict__ kin,
                                               short* __restrict__ Kp) {
    const int tile = blockIdx.x;       // 0..127 (old rows only: s < PREV_)
    const int g = blockIdx.y;          // 0..3
    const int s0 = tile * 32;
    const int tid = threadIdx.x;
    short* dst = Kp + (size_t)(g * NT_ + tile) * 1024 * 8;
    for (int p = 0; p < 4; ++p) {
        int cid = p * 256 + tid;       // 0..1023
        int row = cid >> 5, c = cid & 31;
        short8 v = ld8(&kin[((size_t)(s0 + row) * KV_ + g) * 256 + c * 8]);
        *(short8*)&dst[(size_t)kslot(row, c) * 8] = v;
    }
}

// ---------------- V -> packed Vp[g][tile][1024 chunks] (tile-blocked transpose)
__global__ __launch_bounds__(256) void transpose_v(const float* __restrict__ vin,
                                                   const float* __restrict__ vnew,
                                                   short* __restrict__ Vp) {
    __shared__ short tile[64][65];
    const int g = blockIdx.z;
    const int d0 = blockIdx.y * 64;
    const int s0 = blockIdx.x * 64;
    const int tid = threadIdx.x;
    for (int p = 0; p < 16; ++p) {
        int idx = p * 256 + tid;
        int r = idx >> 6, cc = idx & 63;   // r = s offset, cc = d offset
        int s = s0 + r, d = d0 + cc;
        float v;
        if (s < PREV_) v = vin[((size_t)s * KV_ + g) * 256 + d];
        else           v = vnew[(size_t)(s - PREV_) * 1024 + g * 256 + d];
        tile[r][cc] = bfbits(v);
    }
    __syncthreads();
    for (int p = 0; p < 16; ++p) {
        int idx = p * 256 + tid;
        int r = idx >> 6, cc = idx & 63;   // r = d offset, cc = s offset
        int s = s0 + cc, d = d0 + r;
        int tl = s >> 5, jj = s & 31;
        Vp[((size_t)(g * NT_ + tl) * 1024 + vslot(d, jj >> 3)) * 8 + (jj & 7)] = tile[cc][r];
    }
}

// ---------------- zero the pacing-barrier counter
__global__ void init_bar(unsigned* bar) {
    if (threadIdx.x == 0) bar[0] = 0u;
}

// monotonic grid barrier (pacing only — correctness never depends on it).
// All 512 blocks co-resident: LDS 68KB -> exactly 2 blocks/CU x 256 CUs.
__device__ __forceinline__ void gbar(unsigned* bar, unsigned target) {
    __syncthreads();
    if (threadIdx.x == 0) {
        __threadfence();
        atomicAdd(bar, 1u);
        while (atomicAdd(bar, 0u) < target) __builtin_amdgcn_s_sleep(8);
    }
    __syncthreads();
}

// ---------------- flash attention v9: phase-locked walk + NS=2 key-split.
// 512 blocks (h, 64 q-rows, ns); ns=0 walks tiles 0..95, ns=1 walks 96..191,
// all phase-locked via a pacing barrier every CHT_ tiles (live K/V footprint
// 4g x 256KB x 2 ranges = 2MB chip-wide <= per-XCD L2). 2 blocks/CU => 2
// waves/SIMD so one block's barrier/vmcnt stall hides under the other's MFMA.
// Outputs unnormalized partials (m,l,O) -> cheap 2-way combine.
__global__ __launch_bounds__(256, 2) void attn(const __hip_bfloat16* __restrict__ Qr,  // [H][T][256]
                                               const short* __restrict__ Kp,           // [KV][NT][1024][8]
                                               const short* __restrict__ Vp,           // [KV][NT][1024][8]
                                               short* __restrict__ Po,                 // per (h,tq,ns): [ni16][lane64][r4]
                                               float* __restrict__ Pm,
                                               float* __restrict__ Pl,
                                               unsigned* __restrict__ bar) {
    __shared__ __align__(16) short Ks[2][8192];   // packed K tile, double-buffered (32 KB)
    __shared__ __align__(16) short Vs[2][8192];   // packed V tile, double-buffered (32 KB)
    __shared__ __align__(16) short Pls[4][512];   // per-wave P, packed A-layout (4 KB)
    const int b = (int)blockIdx.x;                // 0..511
    const int h = b >> 6;                         // head 0..7
    const int jq = (b >> 1) & 31;                 // q-block of 64 rows
    const int ns = b & 1;                         // key split 0..1
    const int g = h >> 1;
    const int qbase = jq * 64;
    const int tid = threadIdx.x;                  // 0..255
    const int w = tid >> 6, lane = tid & 63, quad = lane >> 4, lr = lane & 15;
    const int t0 = qbase + w * 16;

    const short* Qb = (const short*)Qr + ((size_t)h * T_ + t0) * 256;
    const short* Kg = Kp + (size_t)g * NT_ * 8192;
    const short* Vg = Vp + (size_t)g * NT_ * 8192;

    short8 aq[8];
    for (int kk = 0; kk < 8; ++kk)
        aq[kk] = *(const short8*)(&Qb[(size_t)lr * 256 + kk * 32 + quad * 8]);

    floatx4 o[16] = {};
    float mrow[4] = {-3e38f, -3e38f, -3e38f, -3e38f};
    float lrow[4] = {0.f, 0.f, 0.f, 0.f};
    const float c = SCALE_ * LOG2E_;
    short* pw = &Pls[w][0];

    const int nf_w = (PREV_ + t0) >> 5;                 // this wave's masked tile
    const int nf_b = (PREV_ + qbase + 48) >> 5;         // block's last useful tile
    const int tbeg = ns * TPS_, tendu = tbeg + TPS_;    // uniform walk range

#define STAGE_TILE(buf, tileidx) do {                                          \
        const short* Kt_ = Kg + (size_t)(tileidx) * 8192;                      \
        const short* Vt_ = Vg + (size_t)(tileidx) * 8192;                      \
        for (int p_ = 0; p_ < 4; ++p_) {                                       \
            gld_lds(Kt_ + (p_ * 256 + w * 64 + lane) * 8,                      \
                    &Ks[buf][(p_ * 256 + w * 64) * 8]);                        \
            gld_lds(Vt_ + (p_ * 256 + w * 64 + lane) * 8,                      \
                    &Vs[buf][(p_ * 256 + w * 64) * 8]);                        \
        }                                                                      \
    } while (0)

    if (tbeg <= nf_b) STAGE_TILE(0, tbeg);
    int cur = 0;
    unsigned nbar = 0;
    for (int tile = tbeg; tile < tendu; ++tile) {
        if (tile > tbeg && (tile & (CHT_ - 1)) == 0) { ++nbar; gbar(bar, 512u * nbar); }
        __syncthreads();            // vmcnt(0)+barrier: LDS[cur] staged & visible
        if (tile + 1 < tendu && tile + 1 <= nf_b)   // prefetch next tile under compute
            STAGE_TILE(cur ^ 1, tile + 1);

        if (tile <= nf_w) {
            const int s0 = tile * 32;
            const bool masked = (tile == nf_w);
            const short* Kb = &Ks[cur][0];
            const short* Vb = &Vs[cur][0];

            floatx4 sc[2];
            __builtin_amdgcn_s_setprio(1);
            for (int half = 0; half < 2; ++half) {
                floatx4 accs = {0.f, 0.f, 0.f, 0.f};
                for (int kk = 0; kk < 8; ++kk) {
                    short8 bk = *(const short8*)&Kb[((kk * 2 + half) * 64 + ((quad * 16 + lr) ^ kk)) * 8];
                    accs = __builtin_amdgcn_mfma_f32_16x16x32_bf16(aq[kk], bk, accs, 0, 0, 0);
                }
                sc[half] = accs;
            }
            __builtin_amdgcn_s_setprio(0);
            float mnew[4];
            for (int r = 0; r < 4; ++r) {
                float v0 = sc[0][r] * c, v1 = sc[1][r] * c;
                if (masked) {
                    int limit = PREV_ + t0 + quad * 4 + r;
                    if (s0 + lr > limit)       v0 = -3e38f;
                    if (s0 + 16 + lr > limit)  v1 = -3e38f;
                }
                sc[0][r] = v0; sc[1][r] = v1;
                float mx = fmaxf(v0, v1);
                mx = fmaxf(mx, __shfl_xor(mx, 1));
                mx = fmaxf(mx, __shfl_xor(mx, 2));
                mx = fmaxf(mx, __shfl_xor(mx, 4));
                mx = fmaxf(mx, __shfl_xor(mx, 8));
                mnew[r] = fmaxf(mrow[r], mx);
            }
            float alpha[4];
            for (int r = 0; r < 4; ++r) { alpha[r] = exp2f(mrow[r] - mnew[r]); mrow[r] = mnew[r]; }
            for (int r = 0; r < 4; ++r) {
                float p0 = exp2f(sc[0][r] - mnew[r]);
                float p1 = exp2f(sc[1][r] - mnew[r]);
                sc[0][r] = p0; sc[1][r] = p1;
                float s = p0 + p1;
                s += __shfl_xor(s, 1);
                s += __shfl_xor(s, 2);
                s += __shfl_xor(s, 4);
                s += __shfl_xor(s, 8);
                lrow[r] = lrow[r] * alpha[r] + s;
            }
            bool need = (alpha[0] < 1.f) | (alpha[1] < 1.f) | (alpha[2] < 1.f) | (alpha[3] < 1.f);
            if (__any(need)) {
                for (int ni = 0; ni < 16; ++ni)
                    for (int r = 0; r < 4; ++r) o[ni][r] *= alpha[r];
            }
            // P: D-layout -> packed A-layout in LDS (wave-local; lgkmcnt only)
            for (int half = 0; half < 2; ++half)
                for (int r = 0; r < 4; ++r) {
                    int koff2 = half * 16 + lr;
                    pw[((koff2 >> 3) * 16 + quad * 4 + r) * 8 + (koff2 & 7)] = bfbits(sc[half][r]);
                }
            __asm__ volatile("s_waitcnt lgkmcnt(0)" ::: "memory");
            short8 ap = *(const short8*)&pw[(quad * 16 + lr) * 8];
            __builtin_amdgcn_s_setprio(1);
            for (int ni = 0; ni < 16; ++ni) {
                short8 bv = *(const short8*)&Vb[(ni * 64 + ((quad * 16 + lr) ^ (ni & 7))) * 8];
                o[ni] = __builtin_amdgcn_mfma_f32_16x16x32_bf16(ap, bv, o[ni], 0, 0, 0);
            }
            __builtin_amdgcn_s_setprio(0);
        }
        cur ^= 1;
    }
#undef STAGE_TILE

    // partial epilogue: unnormalized o + (m, l); 512B contiguous per store
    const int tq = jq * 4 + w;
    const size_t pb16 = (((size_t)h * 128 + tq) * NS_ + ns) * 16;
    const size_t pb = pb16 * 256;
    for (int ni = 0; ni < 16; ++ni) {
        union { unsigned long long u; short s4[4]; } pk;
        for (int r = 0; r < 4; ++r) pk.s4[r] = bfbits(o[ni][r]);
        *(unsigned long long*)&Po[pb + (size_t)ni * 256 + lane * 4] = pk.u;
    }
    if (lr == 0)
        for (int r = 0; r < 4; ++r) {
            Pm[pb16 + quad * 4 + r] = mrow[r];
            Pl[pb16 + quad * 4 + r] = lrow[r];
        }
}

// ---------------- combine split-s partials -> ctx[T][H*256] bf16
__global__ __launch_bounds__(256) void attn_combine(const short* __restrict__ Po,
                                                    const float* __restrict__ Pm,
                                                    const float* __restrict__ Pl,
                                                    __hip_bfloat16* __restrict__ ctx) {
    const int h = blockIdx.x;
    const int tt = blockIdx.y;
    const int tid = threadIdx.x;
    __shared__ float wgt[NS_][16];
    const size_t b = ((size_t)h * 128 + tt) * NS_;
    if (tid < 16) {
        const int row = tid;
        float m[NS_], l[NS_];
        float M = -3e38f;
        for (int ns = 0; ns < NS_; ++ns) {
            m[ns] = Pm[(b + ns) * 16 + row];
            l[ns] = Pl[(b + ns) * 16 + row];
            M = fmaxf(M, m[ns]);
        }
        float denom = 0.f, wv[NS_];
        for (int ns = 0; ns < NS_; ++ns) {
            wv[ns] = exp2f(m[ns] - M);
            denom += wv[ns] * l[ns];
        }
        float rd = 1.f / denom;
        for (int ns = 0; ns < NS_; ++ns) wgt[ns][row] = wv[ns] * rd;
    }
    __syncthreads();
    const int d = tid;
    const int ni = d >> 4, dl = d & 15;
    for (int row = 0; row < 16; ++row) {
        float acc = 0.f;
        // element (row, d): lane = (row>>2)*16 + (d&15), r = row&3, ni = d>>4
        const size_t ib = (size_t)ni * 256 + ((row >> 2) * 16 + dl) * 4 + (row & 3);
        for (int ns = 0; ns < NS_; ++ns)
            acc += wgt[ns][row] * b2f(Po[(b + ns) * 4096 + ib]);
        int t = tt * 16 + row;
        ctx[(size_t)t * (H_ * 256) + h * 256 + d] = __hip_bfloat16(acc);
    }
}

extern "C" void kernel_launch(void* const* d_in, const int* in_sizes, int n_in,
                              void* d_out, int out_size, void* d_ws, size_t ws_size,
                              hipStream_t stream) {
    const float* x       = (const float*)d_in[0];
    const float* Wq      = (const float*)d_in[1];
    const float* Wk      = (const float*)d_in[2];
    const float* Wv      = (const float*)d_in[3];
    const float* Wo      = (const float*)d_in[4];
    const float* q_scale = (const float*)d_in[5];
    const float* k_scale = (const float*)d_in[6];
    const float* k_cache = (const float*)d_in[7];
    const float* v_cache = (const float*)d_in[8];
    const float* cosd    = (const float*)d_in[9];
    const float* sind    = (const float*)d_in[10];
    float* out = (float*)d_out;   // reference output dtype is float32

    char* p = (char*)d_ws;
    float* q_f32 = (float*)p;            p += (size_t)T_ * 2048 * 4;   // 16 MiB
    float* k_f32 = (float*)p;            p += (size_t)T_ * 1024 * 4;   //  8 MiB
    float* v_f32 = (float*)p;            p += (size_t)T_ * 1024 * 4;   //  8 MiB
    __hip_bfloat16* Qr = (__hip_bfloat16*)p;  p += (size_t)H_ * T_ * 256 * 2;
    short* Kp = (short*)p;               p += (size_t)KV_ * NT_ * 1024 * 8 * 2;  // 12 MiB packed K tiles
    short* Vp = (short*)p;               p += (size_t)KV_ * NT_ * 1024 * 8 * 2;  // 12 MiB packed V tiles
    __hip_bfloat16* ctx = (__hip_bfloat16*)p; p += (size_t)T_ * 2048 * 2;
    float* Pm = (float*)p;               p += (size_t)H_ * 128 * NS_ * 16 * 4;
    float* Pl = (float*)p;               p += (size_t)H_ * 128 * NS_ * 16 * 4;
    unsigned* bar = (unsigned*)p;        p += 64;
    // partial O aliases the (dead-by-then) q/k/v fp32 staging: 32 MiB region
    short* Po = (short*)d_ws;            // 8*128*2*16*256*2B = 16.8 MiB

    // fused QKV projection (fp32 out for norm precision)
    gemm_qkv<<<dim3(32, 16), 256, 0, stream>>>(x, Wq, Wk, Wv, q_f32, k_f32, v_f32);

    // norm + rope
    norm_rope_q<<<T_ * H_, 256, 0, stream>>>(q_f32, q_scale, cosd, sind, Qr);
    norm_rope_k<<<T_ * KV_, 256, 0, stream>>>(k_f32, k_scale, cosd, sind, Kp);

    // cache merge into packed tile layouts
    merge_k<<<dim3(PREV_ / 32, KV_), 256, 0, stream>>>(k_cache, Kp);
    transpose_v<<<dim3(SEFF_ / 64, HD_ / 64, KV_), 256, 0, stream>>>(v_cache, v_f32, Vp);

    // attention (flash v9: phase-locked + NS=2 split, 2 blocks/CU) + combine
    init_bar<<<1, 64, 0, stream>>>(bar);
    attn<<<dim3(512), 256, 0, stream>>>(Qr, Kp, Vp, Po, Pm, Pl, bar);
    attn_combine<<<dim3(H_, 128), 256, 0, stream>>>(Po, Pm, Pl, ctx);

    // output projection — fp32 output buffer
    gemm_wo<<<dim3(20, 32), 256, 0, stream>>>(ctx, Wo, out);
}

// Round 6
// 801.447 us; speedup vs baseline: 1.1261x; 1.1261x over previous
//
#include <hip/hip_runtime.h>
#include <hip/hip_bf16.h>

#define T_ 2048
#define D_ 2560
#define H_ 8
#define KV_ 4
#define HD_ 256
#define S_ 8192
#define PREV_ 4096
#define SEFF_ 6144
#define NT_ 192          // SEFF/32 key tiles
#define NS_ 2            // key-dim splits
#define TPS_ 96          // tiles per split (uniform absolute ranges)
#define CHT_ 8           // tiles per pacing chunk (live footprint 4g*256KB*2 = 2MB)
#define SCALE_ 0.0625f
#define LOG2E_ 1.44269504088896f

typedef __attribute__((ext_vector_type(8))) short short8;
typedef __attribute__((ext_vector_type(4))) float floatx4;

__device__ inline short8 ld8(const __hip_bfloat16* p) { return *(const short8*)p; }
__device__ inline short8 ld8(const float* p) {
    float4 a = *(const float4*)p;
    float4 b = *(const float4*)(p + 4);
    union { short8 s; __hip_bfloat16 h[8]; } u;
    u.h[0] = __hip_bfloat16(a.x); u.h[1] = __hip_bfloat16(a.y);
    u.h[2] = __hip_bfloat16(a.z); u.h[3] = __hip_bfloat16(a.w);
    u.h[4] = __hip_bfloat16(b.x); u.h[5] = __hip_bfloat16(b.y);
    u.h[6] = __hip_bfloat16(b.z); u.h[7] = __hip_bfloat16(b.w);
    return u.s;
}

__device__ inline short bfbits(float x) {
    __hip_bfloat16 h(x);
    short s;
    __builtin_memcpy(&s, &h, 2);
    return s;
}

__device__ inline float b2f(short u) {
    unsigned int x = ((unsigned int)(unsigned short)u) << 16;
    float f; __builtin_memcpy(&f, &x, 4); return f;
}

// async global -> LDS, 16B per lane, dest = wave-uniform base + lane*16
__device__ __forceinline__ void gld_lds(const short* g, short* l) {
    __builtin_amdgcn_global_load_lds(
        (const __attribute__((address_space(1))) unsigned int*)(const void*)g,
        (__attribute__((address_space(3))) unsigned int*)(void*)l,
        16, 0, 0);
}

// Packed K/V tile layouts (16B chunk slot within a 32-key tile) — the exact
// layouts attn's MFMA fragment reads use; producers bake them into global.
__device__ __forceinline__ int kslot(int row, int c) {   // row 0..31 (key), c 0..31 (16B chunk of 256-dim)
    int kk = c >> 2, qd = c & 3, hf = row >> 4, lrr = row & 15;
    return (kk * 2 + hf) * 64 + ((qd * 16 + lrr) ^ kk);
}
__device__ __forceinline__ int vslot(int d, int c) {     // d 0..255 (dim), c 0..3 (16B chunk of 32 keys)
    int ni = d >> 4, lrr = d & 15;
    return ni * 64 + ((c * 16 + lrr) ^ (ni & 7));
}

// ---------------- fused QKV GEMM: 128x128 tiles over N=4096 (Wq|Wk|Wv)
__global__ __launch_bounds__(256) void gemm_qkv(const float* __restrict__ A,   // x [2048][2560]
                                                const float* __restrict__ Wq,
                                                const float* __restrict__ Wk,
                                                const float* __restrict__ Wv,
                                                float* __restrict__ qo,        // [2048][2048]
                                                float* __restrict__ ko,        // [2048][1024]
                                                float* __restrict__ vo) {      // [2048][1024]
    __shared__ __align__(16) __hip_bfloat16 As[128 * 40];
    __shared__ __align__(16) __hip_bfloat16 Bs[128 * 40];
    const int K = D_;
    const int tid = threadIdx.x;
    const int bm = (int)blockIdx.y * 128, bn = (int)blockIdx.x * 128;
    const int w = tid >> 6, lane = tid & 63, quad = lane >> 4, lr = lane & 15;
    const int wm = (w >> 1) * 64, wn = (w & 1) * 64;
    floatx4 acc[4][4] = {};
    const int row = tid >> 2;
    const int col = (tid & 3) * 8;

    const float* Bp; float* Co; int nb, ldo;
    if (bn < 2048)      { Bp = Wq + (size_t)bn * K;          Co = qo; nb = bn;        ldo = 2048; }
    else if (bn < 3072) { Bp = Wk + (size_t)(bn - 2048) * K; Co = ko; nb = bn - 2048; ldo = 1024; }
    else                { Bp = Wv + (size_t)(bn - 3072) * K; Co = vo; nb = bn - 3072; ldo = 1024; }

    for (int k0 = 0; k0 < K; k0 += 32) {
        __syncthreads();
        for (int p = 0; p < 2; ++p) {
            int r = row + p * 64;
            *(short8*)(&As[r * 40 + col]) = ld8(&A[(size_t)(bm + r) * K + k0 + col]);
            *(short8*)(&Bs[r * 40 + col]) = ld8(&Bp[(size_t)r * K + k0 + col]);
        }
        __syncthreads();
        short8 a[4], b[4];
        for (int mi = 0; mi < 4; ++mi)
            a[mi] = *(const short8*)(&As[(wm + mi * 16 + lr) * 40 + quad * 8]);
        for (int ni = 0; ni < 4; ++ni)
            b[ni] = *(const short8*)(&Bs[(wn + ni * 16 + lr) * 40 + quad * 8]);
        for (int mi = 0; mi < 4; ++mi)
            for (int ni = 0; ni < 4; ++ni)
                acc[mi][ni] = __builtin_amdgcn_mfma_f32_16x16x32_bf16(a[mi], b[ni], acc[mi][ni], 0, 0, 0);
    }
    for (int mi = 0; mi < 4; ++mi)
        for (int ni = 0; ni < 4; ++ni)
            for (int r = 0; r < 4; ++r) {
                int m = bm + wm + mi * 16 + quad * 4 + r;
                int n = nb + wn + ni * 16 + lr;
                Co[(size_t)m * ldo + n] = acc[mi][ni][r];
            }
}

// ---------------- Wo GEMM: 64(M)x128(N) tiles; A=ctx bf16, B=Wo fp32, C=out fp32
__global__ __launch_bounds__(256) void gemm_wo(const __hip_bfloat16* __restrict__ A,  // [2048][2048]
                                               const float* __restrict__ Bm,          // [2560][2048]
                                               float* __restrict__ C) {               // [2048][2560]
    __shared__ __align__(16) __hip_bfloat16 As[64 * 40];
    __shared__ __align__(16) __hip_bfloat16 Bs[128 * 40];
    const int K = 2048, N = D_;
    const int tid = threadIdx.x;
    const int bm = (int)blockIdx.y * 64, bn = (int)blockIdx.x * 128;
    const int w = tid >> 6, lane = tid & 63, quad = lane >> 4, lr = lane & 15;
    const int wn = w * 32;
    floatx4 acc[4][2] = {};
    const int row = tid >> 2;
    const int col = (tid & 3) * 8;

    for (int k0 = 0; k0 < K; k0 += 32) {
        __syncthreads();
        *(short8*)(&As[row * 40 + col]) = ld8(&A[(size_t)(bm + row) * K + k0 + col]);
        for (int p = 0; p < 2; ++p) {
            int r = row + p * 64;
            *(short8*)(&Bs[r * 40 + col]) = ld8(&Bm[(size_t)(bn + r) * K + k0 + col]);
        }
        __syncthreads();
        short8 a[4], b[2];
        for (int mi = 0; mi < 4; ++mi)
            a[mi] = *(const short8*)(&As[(mi * 16 + lr) * 40 + quad * 8]);
        for (int ni = 0; ni < 2; ++ni)
            b[ni] = *(const short8*)(&Bs[(wn + ni * 16 + lr) * 40 + quad * 8]);
        for (int mi = 0; mi < 4; ++mi)
            for (int ni = 0; ni < 2; ++ni)
                acc[mi][ni] = __builtin_amdgcn_mfma_f32_16x16x32_bf16(a[mi], b[ni], acc[mi][ni], 0, 0, 0);
    }
    for (int mi = 0; mi < 4; ++mi)
        for (int ni = 0; ni < 2; ++ni)
            for (int r = 0; r < 4; ++r) {
                int m = bm + mi * 16 + quad * 4 + r;
                int n = bn + wn + ni * 16 + lr;
                C[(size_t)m * N + n] = acc[mi][ni][r];
            }
}

// ---------------- RMSNorm + RoPE (fp32) for Q, output bf16 [head][t][256]
__global__ __launch_bounds__(256) void norm_rope_q(const float* __restrict__ src,
                                                   const float* __restrict__ scale,
                                                   const float* __restrict__ cosd,
                                                   const float* __restrict__ sind,
                                                   __hip_bfloat16* __restrict__ dst) {
    const int rowid = blockIdx.x;
    const int t = rowid / H_, hh = rowid % H_;
    const int d = threadIdx.x;
    __shared__ float ybuf[256];
    __shared__ float wsum[4];
    float x = src[(size_t)t * (H_ * 256) + hh * 256 + d];
    float ss = x * x;
    for (int m = 1; m < 64; m <<= 1) ss += __shfl_xor(ss, m);
    if ((d & 63) == 0) wsum[d >> 6] = ss;
    __syncthreads();
    float tot = wsum[0] + wsum[1] + wsum[2] + wsum[3];
    float inv = rsqrtf(tot * (1.0f / 256.0f) + 1e-6f);
    float y = x * inv * (1.0f + scale[d]);
    ybuf[d] = y;
    __syncthreads();
    float rot = (d < 128) ? -ybuf[d + 128] : ybuf[d - 128];
    float cv = cosd[(size_t)t * 256 + d];
    float sv = sind[(size_t)t * 256 + d];
    float out = y * cv + rot * sv;
    dst[((size_t)hh * T_ + t) * 256 + d] = __hip_bfloat16(out);
}

// ---------------- RMSNorm + RoPE for new K rows -> packed Kp layout
__global__ __launch_bounds__(256) void norm_rope_k(const float* __restrict__ src,
                                                   const float* __restrict__ scale,
                                                   const float* __restrict__ cosd,
                                                   const float* __restrict__ sind,
                                                   short* __restrict__ Kp) {
    const int rowid = blockIdx.x;
    const int t = rowid / KV_, g = rowid % KV_;
    const int d = threadIdx.x;
    __shared__ float ybuf[256];
    __shared__ float wsum[4];
    float x = src[(size_t)t * (KV_ * 256) + g * 256 + d];
    float ss = x * x;
    for (int m = 1; m < 64; m <<= 1) ss += __shfl_xor(ss, m);
    if ((d & 63) == 0) wsum[d >> 6] = ss;
    __syncthreads();
    float tot = wsum[0] + wsum[1] + wsum[2] + wsum[3];
    float inv = rsqrtf(tot * (1.0f / 256.0f) + 1e-6f);
    float y = x * inv * (1.0f + scale[d]);
    ybuf[d] = y;
    __syncthreads();
    float rot = (d < 128) ? -ybuf[d + 128] : ybuf[d - 128];
    float cv = cosd[(size_t)t * 256 + d];
    float sv = sind[(size_t)t * 256 + d];
    float out = y * cv + rot * sv;
    const int s = t + PREV_;
    const int tile = s >> 5, row = s & 31;
    Kp[((size_t)(g * NT_ + tile) * 1024 + kslot(row, d >> 3)) * 8 + (d & 7)] = bfbits(out);
}

// ---------------- old K cache (fp32) -> packed Kp[g][tile][1024 chunks]
__global__ __launch_bounds__(256) void merge_k(const float* __restrict__ kin,
                                               short* __restrict__ Kp) {
    const int tile = blockIdx.x;       // 0..127 (old rows only: s < PREV_)
    const int g = blockIdx.y;          // 0..3
    const int s0 = tile * 32;
    const int tid = threadIdx.x;
    short* dst = Kp + (size_t)(g * NT_ + tile) * 1024 * 8;
    for (int p = 0; p < 4; ++p) {
        int cid = p * 256 + tid;       // 0..1023
        int row = cid >> 5, c = cid & 31;
        short8 v = ld8(&kin[((size_t)(s0 + row) * KV_ + g) * 256 + c * 8]);
        *(short8*)&dst[(size_t)kslot(row, c) * 8] = v;
    }
}

// ---------------- V -> packed Vp[g][tile][1024 chunks] (tile-blocked transpose)
__global__ __launch_bounds__(256) void transpose_v(const float* __restrict__ vin,
                                                   const float* __restrict__ vnew,
                                                   short* __restrict__ Vp) {
    __shared__ short tile[64][65];
    const int g = blockIdx.z;
    const int d0 = blockIdx.y * 64;
    const int s0 = blockIdx.x * 64;
    const int tid = threadIdx.x;
    for (int p = 0; p < 16; ++p) {
        int idx = p * 256 + tid;
        int r = idx >> 6, cc = idx & 63;   // r = s offset, cc = d offset
        int s = s0 + r, d = d0 + cc;
        float v;
        if (s < PREV_) v = vin[((size_t)s * KV_ + g) * 256 + d];
        else           v = vnew[(size_t)(s - PREV_) * 1024 + g * 256 + d];
        tile[r][cc] = bfbits(v);
    }
    __syncthreads();
    for (int p = 0; p < 16; ++p) {
        int idx = p * 256 + tid;
        int r = idx >> 6, cc = idx & 63;   // r = d offset, cc = s offset
        int s = s0 + cc, d = d0 + r;
        int tl = s >> 5, jj = s & 31;
        Vp[((size_t)(g * NT_ + tl) * 1024 + vslot(d, jj >> 3)) * 8 + (jj & 7)] = tile[cc][r];
    }
}

// ---------------- zero the pacing-barrier counters (8, padded to 128B apart)
__global__ void init_bar(unsigned* bar) {
    if (threadIdx.x < 8 * 32) bar[threadIdx.x] = 0u;
}

// monotonic grid barrier, pacing-only. Arrivals spread over 8 padded counters
// (parallel fabric paths); polling via relaxed agent-scope atomic LOADS (no
// RMW storm). Correctness never depends on this barrier.
__device__ __forceinline__ void gbar(unsigned* bar, int myq, unsigned target) {
    __syncthreads();
    if (threadIdx.x == 0) {
        __threadfence();
        atomicAdd(&bar[myq * 32], 1u);
        unsigned sum = 0;
        for (int i = 0; i < 8; ++i)
            sum += __hip_atomic_load(&bar[i * 32], __ATOMIC_RELAXED, __HIP_MEMORY_SCOPE_AGENT);
        while (sum < target) {
            __builtin_amdgcn_s_sleep(8);
            sum = 0;
            for (int i = 0; i < 8; ++i)
                sum += __hip_atomic_load(&bar[i * 32], __ATOMIC_RELAXED, __HIP_MEMORY_SCOPE_AGENT);
        }
    }
    __syncthreads();
}

// ---------------- flash attention v10: phase-locked walk + NS=2 key-split,
// cheap load-poll barrier, rotated within-chunk tile order (de-correlates
// co-resident blocks' staging bursts; live set per chunk unchanged), and
// MFMA-computed softmax denominator (ones-B trick replaces 16-shfl sum).
__global__ __launch_bounds__(256, 2) void attn(const __hip_bfloat16* __restrict__ Qr,  // [H][T][256]
                                               const short* __restrict__ Kp,           // [KV][NT][1024][8]
                                               const short* __restrict__ Vp,           // [KV][NT][1024][8]
                                               short* __restrict__ Po,                 // per (h,tq,ns): [ni16][lane64][r4]
                                               float* __restrict__ Pm,
                                               float* __restrict__ Pl,
                                               unsigned* __restrict__ bar) {
    __shared__ __align__(16) short Ks[2][8192];   // packed K tile, double-buffered (32 KB)
    __shared__ __align__(16) short Vs[2][8192];   // packed V tile, double-buffered (32 KB)
    __shared__ __align__(16) short Pls[4][512];   // per-wave P, packed A-layout (4 KB)
    const int b = (int)blockIdx.x;                // 0..511
    const int h = b >> 6;                         // head 0..7
    const int jq = (b >> 1) & 31;                 // q-block of 64 rows
    const int ns = b & 1;                         // key split 0..1
    const int g = h >> 1;
    const int qbase = jq * 64;
    const int tid = threadIdx.x;                  // 0..255
    const int w = tid >> 6, lane = tid & 63, quad = lane >> 4, lr = lane & 15;
    const int t0 = qbase + w * 16;
    const int myq = b & 7;                        // arrival counter lane
    const int rot = b & (CHT_ - 1);               // within-chunk rotation

    const short* Qb = (const short*)Qr + ((size_t)h * T_ + t0) * 256;
    const short* Kg = Kp + (size_t)g * NT_ * 8192;
    const short* Vg = Vp + (size_t)g * NT_ * 8192;

    short8 aq[8];
    for (int kk = 0; kk < 8; ++kk)
        aq[kk] = *(const short8*)(&Qb[(size_t)lr * 256 + kk * 32 + quad * 8]);

    floatx4 o[16] = {};
    floatx4 lacc = {0.f, 0.f, 0.f, 0.f};          // softmax denom via MFMA-ones
    float mrow[4] = {-3e38f, -3e38f, -3e38f, -3e38f};
    const float c = SCALE_ * LOG2E_;
    short* pw = &Pls[w][0];
    const short oneb = (short)0x3F80;             // bf16(1.0)
    const short8 ones8 = {oneb, oneb, oneb, oneb, oneb, oneb, oneb, oneb};

    const int nf_w = (PREV_ + t0) >> 5;                 // this wave's masked tile
    const int nf_b = (PREV_ + qbase + 48) >> 5;         // block's last useful tile
    const int cbeg = (ns * TPS_) / CHT_;                // chunk walk range
    const int cend = cbeg + TPS_ / CHT_;

#define STAGE_TILE(buf, tileidx) do {                                          \
        const short* Kt_ = Kg + (size_t)(tileidx) * 8192;                      \
        const short* Vt_ = Vg + (size_t)(tileidx) * 8192;                      \
        for (int p_ = 0; p_ < 4; ++p_) {                                       \
            gld_lds(Kt_ + (p_ * 256 + w * 64 + lane) * 8,                      \
                    &Ks[buf][(p_ * 256 + w * 64) * 8]);                        \
            gld_lds(Vt_ + (p_ * 256 + w * 64 + lane) * 8,                      \
                    &Vs[buf][(p_ * 256 + w * 64) * 8]);                        \
        }                                                                      \
    } while (0)

    // prologue: stage first tile of the rotated sequence
    {
        const int tf = cbeg * CHT_ + rot;
        if (tf <= nf_b) STAGE_TILE(0, tf);
    }
    int cur = 0;
    unsigned nbar = 0;
    for (int ci = cbeg; ci < cend; ++ci) {
        for (int i = 0; i < CHT_; ++i) {
            const int tile = ci * CHT_ + ((i + rot) & (CHT_ - 1));
            if (i == 0 && ci > cbeg) { ++nbar; gbar(bar, myq, 512u * nbar); }
            else __syncthreads();   // vmcnt(0)+barrier: LDS[cur] staged & visible
            // prefetch next tile in the rotated sequence into LDS[cur^1]
            {
                int ni_ = i + 1, nc_ = ci;
                if (ni_ == CHT_) { ni_ = 0; ++nc_; }
                if (nc_ < cend) {
                    const int nt_ = nc_ * CHT_ + ((ni_ + rot) & (CHT_ - 1));
                    if (nt_ <= nf_b) STAGE_TILE(cur ^ 1, nt_);
                }
            }

            if (tile <= nf_w) {
                const int s0 = tile * 32;
                const bool masked = (tile == nf_w);
                const short* Kb = &Ks[cur][0];
                const short* Vb = &Vs[cur][0];

                floatx4 sc[2];
                __builtin_amdgcn_s_setprio(1);
                for (int half = 0; half < 2; ++half) {
                    floatx4 accs = {0.f, 0.f, 0.f, 0.f};
                    for (int kk = 0; kk < 8; ++kk) {
                        short8 bk = *(const short8*)&Kb[((kk * 2 + half) * 64 + ((quad * 16 + lr) ^ kk)) * 8];
                        accs = __builtin_amdgcn_mfma_f32_16x16x32_bf16(aq[kk], bk, accs, 0, 0, 0);
                    }
                    sc[half] = accs;
                }
                __builtin_amdgcn_s_setprio(0);
                float mnew[4];
                for (int r = 0; r < 4; ++r) {
                    float v0 = sc[0][r] * c, v1 = sc[1][r] * c;
                    if (masked) {
                        int limit = PREV_ + t0 + quad * 4 + r;
                        if (s0 + lr > limit)       v0 = -3e38f;
                        if (s0 + 16 + lr > limit)  v1 = -3e38f;
                    }
                    sc[0][r] = v0; sc[1][r] = v1;
                    float mx = fmaxf(v0, v1);
                    mx = fmaxf(mx, __shfl_xor(mx, 1));
                    mx = fmaxf(mx, __shfl_xor(mx, 2));
                    mx = fmaxf(mx, __shfl_xor(mx, 4));
                    mx = fmaxf(mx, __shfl_xor(mx, 8));
                    mnew[r] = fmaxf(mrow[r], mx);
                }
                float alpha[4];
                for (int r = 0; r < 4; ++r) { alpha[r] = exp2f(mrow[r] - mnew[r]); mrow[r] = mnew[r]; }
                for (int r = 0; r < 4; ++r) {
                    sc[0][r] = exp2f(sc[0][r] - mnew[r]);
                    sc[1][r] = exp2f(sc[1][r] - mnew[r]);
                }
                bool need = (alpha[0] < 1.f) | (alpha[1] < 1.f) | (alpha[2] < 1.f) | (alpha[3] < 1.f);
                if (__any(need)) {
                    for (int ni = 0; ni < 16; ++ni)
                        for (int r = 0; r < 4; ++r) o[ni][r] *= alpha[r];
                    for (int r = 0; r < 4; ++r) lacc[r] *= alpha[r];
                }
                // P: D-layout -> packed A-layout in LDS (wave-local; lgkmcnt only)
                for (int half = 0; half < 2; ++half)
                    for (int r = 0; r < 4; ++r) {
                        int koff2 = half * 16 + lr;
                        pw[((koff2 >> 3) * 16 + quad * 4 + r) * 8 + (koff2 & 7)] = bfbits(sc[half][r]);
                    }
                __asm__ volatile("s_waitcnt lgkmcnt(0)" ::: "memory");
                short8 ap = *(const short8*)&pw[(quad * 16 + lr) * 8];
                __builtin_amdgcn_s_setprio(1);
                lacc = __builtin_amdgcn_mfma_f32_16x16x32_bf16(ap, ones8, lacc, 0, 0, 0);
                for (int ni = 0; ni < 16; ++ni) {
                    short8 bv = *(const short8*)&Vb[(ni * 64 + ((quad * 16 + lr) ^ (ni & 7))) * 8];
                    o[ni] = __builtin_amdgcn_mfma_f32_16x16x32_bf16(ap, bv, o[ni], 0, 0, 0);
                }
                __builtin_amdgcn_s_setprio(0);
            }
            cur ^= 1;
        }
    }
#undef STAGE_TILE

    // partial epilogue: unnormalized o + (m, l); 512B contiguous per store
    const int tq = jq * 4 + w;
    const size_t pb16 = (((size_t)h * 128 + tq) * NS_ + ns) * 16;
    const size_t pb = pb16 * 256;
    for (int ni = 0; ni < 16; ++ni) {
        union { unsigned long long u; short s4[4]; } pk;
        for (int r = 0; r < 4; ++r) pk.s4[r] = bfbits(o[ni][r]);
        *(unsigned long long*)&Po[pb + (size_t)ni * 256 + lane * 4] = pk.u;
    }
    if (lr == 0)
        for (int r = 0; r < 4; ++r) {
            Pm[pb16 + quad * 4 + r] = mrow[r];
            Pl[pb16 + quad * 4 + r] = lacc[r];
        }
}

// ---------------- combine split-s partials -> ctx[T][H*256] bf16
__global__ __launch_bounds__(256) void attn_combine(const short* __restrict__ Po,
                                                    const float* __restrict__ Pm,
                                                    const float* __restrict__ Pl,
                                                    __hip_bfloat16* __restrict__ ctx) {
    const int h = blockIdx.x;
    const int tt = blockIdx.y;
    const int tid = threadIdx.x;
    __shared__ float wgt[NS_][16];
    const size_t b = ((size_t)h * 128 + tt) * NS_;
    if (tid < 16) {
        const int row = tid;
        float m[NS_], l[NS_];
        float M = -3e38f;
        for (int ns = 0; ns < NS_; ++ns) {
            m[ns] = Pm[(b + ns) * 16 + row];
            l[ns] = Pl[(b + ns) * 16 + row];
            M = fmaxf(M, m[ns]);
        }
        float denom = 0.f, wv[NS_];
        for (int ns = 0; ns < NS_; ++ns) {
            wv[ns] = exp2f(m[ns] - M);
            denom += wv[ns] * l[ns];
        }
        float rd = 1.f / denom;
        for (int ns = 0; ns < NS_; ++ns) wgt[ns][row] = wv[ns] * rd;
    }
    __syncthreads();
    const int d = tid;
    const int ni = d >> 4, dl = d & 15;
    for (int row = 0; row < 16; ++row) {
        float acc = 0.f;
        // element (row, d): lane = (row>>2)*16 + (d&15), r = row&3, ni = d>>4
        const size_t ib = (size_t)ni * 256 + ((row >> 2) * 16 + dl) * 4 + (row & 3);
        for (int ns = 0; ns < NS_; ++ns)
            acc += wgt[ns][row] * b2f(Po[(b + ns) * 4096 + ib]);
        int t = tt * 16 + row;
        ctx[(size_t)t * (H_ * 256) + h * 256 + d] = __hip_bfloat16(acc);
    }
}

extern "C" void kernel_launch(void* const* d_in, const int* in_sizes, int n_in,
                              void* d_out, int out_size, void* d_ws, size_t ws_size,
                              hipStream_t stream) {
    const float* x       = (const float*)d_in[0];
    const float* Wq      = (const float*)d_in[1];
    const float* Wk      = (const float*)d_in[2];
    const float* Wv      = (const float*)d_in[3];
    const float* Wo      = (const float*)d_in[4];
    const float* q_scale = (const float*)d_in[5];
    const float* k_scale = (const float*)d_in[6];
    const float* k_cache = (const float*)d_in[7];
    const float* v_cache = (const float*)d_in[8];
    const float* cosd    = (const float*)d_in[9];
    const float* sind    = (const float*)d_in[10];
    float* out = (float*)d_out;   // reference output dtype is float32

    char* p = (char*)d_ws;
    float* q_f32 = (float*)p;            p += (size_t)T_ * 2048 * 4;   // 16 MiB
    float* k_f32 = (float*)p;            p += (size_t)T_ * 1024 * 4;   //  8 MiB
    float* v_f32 = (float*)p;            p += (size_t)T_ * 1024 * 4;   //  8 MiB
    __hip_bfloat16* Qr = (__hip_bfloat16*)p;  p += (size_t)H_ * T_ * 256 * 2;
    short* Kp = (short*)p;               p += (size_t)KV_ * NT_ * 1024 * 8 * 2;  // 12 MiB packed K tiles
    short* Vp = (short*)p;               p += (size_t)KV_ * NT_ * 1024 * 8 * 2;  // 12 MiB packed V tiles
    __hip_bfloat16* ctx = (__hip_bfloat16*)p; p += (size_t)T_ * 2048 * 2;
    float* Pm = (float*)p;               p += (size_t)H_ * 128 * NS_ * 16 * 4;
    float* Pl = (float*)p;               p += (size_t)H_ * 128 * NS_ * 16 * 4;
    unsigned* bar = (unsigned*)p;        p += 8 * 32 * sizeof(unsigned);
    // partial O aliases the (dead-by-then) q/k/v fp32 staging: 32 MiB region
    short* Po = (short*)d_ws;            // 8*128*2*16*256*2B = 16.8 MiB

    // fused QKV projection (fp32 out for norm precision)
    gemm_qkv<<<dim3(32, 16), 256, 0, stream>>>(x, Wq, Wk, Wv, q_f32, k_f32, v_f32);

    // norm + rope
    norm_rope_q<<<T_ * H_, 256, 0, stream>>>(q_f32, q_scale, cosd, sind, Qr);
    norm_rope_k<<<T_ * KV_, 256, 0, stream>>>(k_f32, k_scale, cosd, sind, Kp);

    // cache merge into packed tile layouts
    merge_k<<<dim3(PREV_ / 32, KV_), 256, 0, stream>>>(k_cache, Kp);
    transpose_v<<<dim3(SEFF_ / 64, HD_ / 64, KV_), 256, 0, stream>>>(v_cache, v_f32, Vp);

    // attention (flash v10: cheap barrier + rotation + mfma-l) + combine
    init_bar<<<1, 256, 0, stream>>>(bar);
    attn<<<dim3(512), 256, 0, stream>>>(Qr, Kp, Vp, Po, Pm, Pl, bar);
    attn_combine<<<dim3(H_, 128), 256, 0, stream>>>(Po, Pm, Pl, ctx);

    // output projection — fp32 output buffer
    gemm_wo<<<dim3(20, 32), 256, 0, stream>>>(ctx, Wo, out);
}

// Round 7
// 649.759 us; speedup vs baseline: 1.3890x; 1.2335x over previous
//
#include <hip/hip_runtime.h>
#include <hip/hip_bf16.h>

#define T_ 2048
#define D_ 2560
#define H_ 8
#define KV_ 4
#define HD_ 256
#define S_ 8192
#define PREV_ 4096
#define SEFF_ 6144
#define NT_ 192          // SEFF/32 key tiles
#define NS_ 2            // key-dim splits (interleaved by pair-of-tiles)
#define NJ_ 48           // iterations per block (NT_ / (2 pairs * NS_))
#define SCALE_ 0.0625f
#define LOG2E_ 1.44269504088896f

typedef __attribute__((ext_vector_type(8))) short short8;
typedef __attribute__((ext_vector_type(4))) float floatx4;

__device__ inline short8 ld8(const __hip_bfloat16* p) { return *(const short8*)p; }
__device__ inline short8 ld8(const float* p) {
    float4 a = *(const float4*)p;
    float4 b = *(const float4*)(p + 4);
    union { short8 s; __hip_bfloat16 h[8]; } u;
    u.h[0] = __hip_bfloat16(a.x); u.h[1] = __hip_bfloat16(a.y);
    u.h[2] = __hip_bfloat16(a.z); u.h[3] = __hip_bfloat16(a.w);
    u.h[4] = __hip_bfloat16(b.x); u.h[5] = __hip_bfloat16(b.y);
    u.h[6] = __hip_bfloat16(b.z); u.h[7] = __hip_bfloat16(b.w);
    return u.s;
}

__device__ inline short bfbits(float x) {
    __hip_bfloat16 h(x);
    short s;
    __builtin_memcpy(&s, &h, 2);
    return s;
}

__device__ inline float b2f(short u) {
    unsigned int x = ((unsigned int)(unsigned short)u) << 16;
    float f; __builtin_memcpy(&f, &x, 4); return f;
}

// async global -> LDS, 16B per lane, dest = wave-uniform base + lane*16
__device__ __forceinline__ void gld_lds(const short* g, short* l) {
    __builtin_amdgcn_global_load_lds(
        (const __attribute__((address_space(1))) unsigned int*)(const void*)g,
        (__attribute__((address_space(3))) unsigned int*)(void*)l,
        16, 0, 0);
}

// Packed K/V tile layouts (16B chunk slot within a 32-key tile) — the exact
// layouts attn's MFMA fragment reads use; producers bake them into global.
__device__ __forceinline__ int kslot(int row, int c) {   // row 0..31 (key), c 0..31 (16B chunk of 256-dim)
    int kk = c >> 2, qd = c & 3, hf = row >> 4, lrr = row & 15;
    return (kk * 2 + hf) * 64 + ((qd * 16 + lrr) ^ kk);
}
__device__ __forceinline__ int vslot(int d, int c) {     // d 0..255 (dim), c 0..3 (16B chunk of 32 keys)
    int ni = d >> 4, lrr = d & 15;
    return ni * 64 + ((c * 16 + lrr) ^ (ni & 7));
}

// ---------------- fused QKV GEMM: 128x128 tiles over N=4096 (Wq|Wk|Wv)
__global__ __launch_bounds__(256) void gemm_qkv(const float* __restrict__ A,   // x [2048][2560]
                                                const float* __restrict__ Wq,
                                                const float* __restrict__ Wk,
                                                const float* __restrict__ Wv,
                                                float* __restrict__ qo,        // [2048][2048]
                                                float* __restrict__ ko,        // [2048][1024]
                                                float* __restrict__ vo) {      // [2048][1024]
    __shared__ __align__(16) __hip_bfloat16 As[128 * 40];
    __shared__ __align__(16) __hip_bfloat16 Bs[128 * 40];
    const int K = D_;
    const int tid = threadIdx.x;
    const int bm = (int)blockIdx.y * 128, bn = (int)blockIdx.x * 128;
    const int w = tid >> 6, lane = tid & 63, quad = lane >> 4, lr = lane & 15;
    const int wm = (w >> 1) * 64, wn = (w & 1) * 64;
    floatx4 acc[4][4] = {};
    const int row = tid >> 2;
    const int col = (tid & 3) * 8;

    const float* Bp; float* Co; int nb, ldo;
    if (bn < 2048)      { Bp = Wq + (size_t)bn * K;          Co = qo; nb = bn;        ldo = 2048; }
    else if (bn < 3072) { Bp = Wk + (size_t)(bn - 2048) * K; Co = ko; nb = bn - 2048; ldo = 1024; }
    else                { Bp = Wv + (size_t)(bn - 3072) * K; Co = vo; nb = bn - 3072; ldo = 1024; }

    for (int k0 = 0; k0 < K; k0 += 32) {
        __syncthreads();
        for (int p = 0; p < 2; ++p) {
            int r = row + p * 64;
            *(short8*)(&As[r * 40 + col]) = ld8(&A[(size_t)(bm + r) * K + k0 + col]);
            *(short8*)(&Bs[r * 40 + col]) = ld8(&Bp[(size_t)r * K + k0 + col]);
        }
        __syncthreads();
        short8 a[4], b[4];
        for (int mi = 0; mi < 4; ++mi)
            a[mi] = *(const short8*)(&As[(wm + mi * 16 + lr) * 40 + quad * 8]);
        for (int ni = 0; ni < 4; ++ni)
            b[ni] = *(const short8*)(&Bs[(wn + ni * 16 + lr) * 40 + quad * 8]);
        for (int mi = 0; mi < 4; ++mi)
            for (int ni = 0; ni < 4; ++ni)
                acc[mi][ni] = __builtin_amdgcn_mfma_f32_16x16x32_bf16(a[mi], b[ni], acc[mi][ni], 0, 0, 0);
    }
    for (int mi = 0; mi < 4; ++mi)
        for (int ni = 0; ni < 4; ++ni)
            for (int r = 0; r < 4; ++r) {
                int m = bm + wm + mi * 16 + quad * 4 + r;
                int n = nb + wn + ni * 16 + lr;
                Co[(size_t)m * ldo + n] = acc[mi][ni][r];
            }
}

// ---------------- Wo GEMM: 64(M)x128(N) tiles; A=ctx bf16, B=Wo fp32, C=out fp32
__global__ __launch_bounds__(256) void gemm_wo(const __hip_bfloat16* __restrict__ A,  // [2048][2048]
                                               const float* __restrict__ Bm,          // [2560][2048]
                                               float* __restrict__ C) {               // [2048][2560]
    __shared__ __align__(16) __hip_bfloat16 As[64 * 40];
    __shared__ __align__(16) __hip_bfloat16 Bs[128 * 40];
    const int K = 2048, N = D_;
    const int tid = threadIdx.x;
    const int bm = (int)blockIdx.y * 64, bn = (int)blockIdx.x * 128;
    const int w = tid >> 6, lane = tid & 63, quad = lane >> 4, lr = lane & 15;
    const int wn = w * 32;
    floatx4 acc[4][2] = {};
    const int row = tid >> 2;
    const int col = (tid & 3) * 8;

    for (int k0 = 0; k0 < K; k0 += 32) {
        __syncthreads();
        *(short8*)(&As[row * 40 + col]) = ld8(&A[(size_t)(bm + row) * K + k0 + col]);
        for (int p = 0; p < 2; ++p) {
            int r = row + p * 64;
            *(short8*)(&Bs[r * 40 + col]) = ld8(&Bm[(size_t)(bn + r) * K + k0 + col]);
        }
        __syncthreads();
        short8 a[4], b[2];
        for (int mi = 0; mi < 4; ++mi)
            a[mi] = *(const short8*)(&As[(mi * 16 + lr) * 40 + quad * 8]);
        for (int ni = 0; ni < 2; ++ni)
            b[ni] = *(const short8*)(&Bs[(wn + ni * 16 + lr) * 40 + quad * 8]);
        for (int mi = 0; mi < 4; ++mi)
            for (int ni = 0; ni < 2; ++ni)
                acc[mi][ni] = __builtin_amdgcn_mfma_f32_16x16x32_bf16(a[mi], b[ni], acc[mi][ni], 0, 0, 0);
    }
    for (int mi = 0; mi < 4; ++mi)
        for (int ni = 0; ni < 2; ++ni)
            for (int r = 0; r < 4; ++r) {
                int m = bm + mi * 16 + quad * 4 + r;
                int n = bn + wn + ni * 16 + lr;
                C[(size_t)m * N + n] = acc[mi][ni][r];
            }
}

// ---------------- RMSNorm + RoPE (fp32) for Q, output bf16 [head][t][256]
__global__ __launch_bounds__(256) void norm_rope_q(const float* __restrict__ src,
                                                   const float* __restrict__ scale,
                                                   const float* __restrict__ cosd,
                                                   const float* __restrict__ sind,
                                                   __hip_bfloat16* __restrict__ dst) {
    const int rowid = blockIdx.x;
    const int t = rowid / H_, hh = rowid % H_;
    const int d = threadIdx.x;
    __shared__ float ybuf[256];
    __shared__ float wsum[4];
    float x = src[(size_t)t * (H_ * 256) + hh * 256 + d];
    float ss = x * x;
    for (int m = 1; m < 64; m <<= 1) ss += __shfl_xor(ss, m);
    if ((d & 63) == 0) wsum[d >> 6] = ss;
    __syncthreads();
    float tot = wsum[0] + wsum[1] + wsum[2] + wsum[3];
    float inv = rsqrtf(tot * (1.0f / 256.0f) + 1e-6f);
    float y = x * inv * (1.0f + scale[d]);
    ybuf[d] = y;
    __syncthreads();
    float rot = (d < 128) ? -ybuf[d + 128] : ybuf[d - 128];
    float cv = cosd[(size_t)t * 256 + d];
    float sv = sind[(size_t)t * 256 + d];
    float out = y * cv + rot * sv;
    dst[((size_t)hh * T_ + t) * 256 + d] = __hip_bfloat16(out);
}

// ---------------- RMSNorm + RoPE for new K rows -> packed Kp layout
__global__ __launch_bounds__(256) void norm_rope_k(const float* __restrict__ src,
                                                   const float* __restrict__ scale,
                                                   const float* __restrict__ cosd,
                                                   const float* __restrict__ sind,
                                                   short* __restrict__ Kp) {
    const int rowid = blockIdx.x;
    const int t = rowid / KV_, g = rowid % KV_;
    const int d = threadIdx.x;
    __shared__ float ybuf[256];
    __shared__ float wsum[4];
    float x = src[(size_t)t * (KV_ * 256) + g * 256 + d];
    float ss = x * x;
    for (int m = 1; m < 64; m <<= 1) ss += __shfl_xor(ss, m);
    if ((d & 63) == 0) wsum[d >> 6] = ss;
    __syncthreads();
    float tot = wsum[0] + wsum[1] + wsum[2] + wsum[3];
    float inv = rsqrtf(tot * (1.0f / 256.0f) + 1e-6f);
    float y = x * inv * (1.0f + scale[d]);
    ybuf[d] = y;
    __syncthreads();
    float rot = (d < 128) ? -ybuf[d + 128] : ybuf[d - 128];
    float cv = cosd[(size_t)t * 256 + d];
    float sv = sind[(size_t)t * 256 + d];
    float out = y * cv + rot * sv;
    const int s = t + PREV_;
    const int tile = s >> 5, row = s & 31;
    Kp[((size_t)(g * NT_ + tile) * 1024 + kslot(row, d >> 3)) * 8 + (d & 7)] = bfbits(out);
}

// ---------------- old K cache (fp32) -> packed Kp[g][tile][1024 chunks]
__global__ __launch_bounds__(256) void merge_k(const float* __restrict__ kin,
                                               short* __restrict__ Kp) {
    const int tile = blockIdx.x;       // 0..127 (old rows only: s < PREV_)
    const int g = blockIdx.y;          // 0..3
    const int s0 = tile * 32;
    const int tid = threadIdx.x;
    short* dst = Kp + (size_t)(g * NT_ + tile) * 1024 * 8;
    for (int p = 0; p < 4; ++p) {
        int cid = p * 256 + tid;       // 0..1023
        int row = cid >> 5, c = cid & 31;
        short8 v = ld8(&kin[((size_t)(s0 + row) * KV_ + g) * 256 + c * 8]);
        *(short8*)&dst[(size_t)kslot(row, c) * 8] = v;
    }
}

// ---------------- V -> packed Vp[g][tile][1024 chunks] (tile-blocked transpose)
__global__ __launch_bounds__(256) void transpose_v(const float* __restrict__ vin,
                                                   const float* __restrict__ vnew,
                                                   short* __restrict__ Vp) {
    __shared__ short tile[64][65];
    const int g = blockIdx.z;
    const int d0 = blockIdx.y * 64;
    const int s0 = blockIdx.x * 64;
    const int tid = threadIdx.x;
    for (int p = 0; p < 16; ++p) {
        int idx = p * 256 + tid;
        int r = idx >> 6, cc = idx & 63;   // r = s offset, cc = d offset
        int s = s0 + r, d = d0 + cc;
        float v;
        if (s < PREV_) v = vin[((size_t)s * KV_ + g) * 256 + d];
        else           v = vnew[(size_t)(s - PREV_) * 1024 + g * 256 + d];
        tile[r][cc] = bfbits(v);
    }
    __syncthreads();
    for (int p = 0; p < 16; ++p) {
        int idx = p * 256 + tid;
        int r = idx >> 6, cc = idx & 63;   // r = d offset, cc = s offset
        int s = s0 + cc, d = d0 + r;
        int tl = s >> 5, jj = s & 31;
        Vp[((size_t)(g * NT_ + tl) * 1024 + vslot(d, jj >> 3)) * 8 + (jj & 7)] = tile[cc][r];
    }
}

// ---------------- zero the pacing-barrier counters (8, padded to 128B apart)
__global__ void init_bar(unsigned* bar) {
    if (threadIdx.x < 8 * 32) bar[threadIdx.x] = 0u;
}

// monotonic grid barrier, pacing-only. Arrivals spread over 8 padded counters;
// polling via relaxed agent-scope atomic LOADS. Correctness never depends on it.
__device__ __forceinline__ void gbar(unsigned* bar, int myq, unsigned target) {
    __syncthreads();
    if (threadIdx.x == 0) {
        __threadfence();
        atomicAdd(&bar[myq * 32], 1u);
        unsigned sum = 0;
        for (int i = 0; i < 8; ++i)
            sum += __hip_atomic_load(&bar[i * 32], __ATOMIC_RELAXED, __HIP_MEMORY_SCOPE_AGENT);
        while (sum < target) {
            __builtin_amdgcn_s_sleep(4);
            sum = 0;
            for (int i = 0; i < 8; ++i)
                sum += __hip_atomic_load(&bar[i * 32], __ATOMIC_RELAXED, __HIP_MEMORY_SCOPE_AGENT);
        }
    }
    __syncthreads();
}

// ---------------- flash attention v11: KVBLK=64 + interleaved balanced split.
// 256 blocks (h, 128 q-rows, ns) x 512 thr (8 waves), 1 block/CU (144KB LDS).
// Each iteration computes TWO 32-key tiles (pair 4j+2ns,+1) from a double-
// buffered 4x16KB pair: one sync, one softmax pass, 4-way QK MFMA ILP per 64
// keys. ns interleaves pairs -> both splits walk the same 16-tile region in
// the same chunk (phase-lock + perfect balance). Pacing barrier every 4 iters.
__global__ __launch_bounds__(512, 2) void attn(const __hip_bfloat16* __restrict__ Qr,  // [H][T][256]
                                               const short* __restrict__ Kp,           // [KV][NT][1024][8]
                                               const short* __restrict__ Vp,           // [KV][NT][1024][8]
                                               short* __restrict__ Po,                 // per (h,tq,ns): [ni16][lane64][r4]
                                               float* __restrict__ Pm,
                                               float* __restrict__ Pl,
                                               unsigned* __restrict__ bar) {
    __shared__ __align__(16) short Ks[2][2][8192];   // K pair, double-buffered (64 KB)
    __shared__ __align__(16) short Vs[2][2][8192];   // V pair, double-buffered (64 KB)
    __shared__ __align__(16) short Pls[8][1024];     // per-wave P (64 keys), A-layout (16 KB)
    const int b = (int)blockIdx.x;                // 0..255
    const int h = b >> 5;                         // head 0..7
    const int jq = (b >> 1) & 15;                 // q-block of 128 rows
    const int ns = b & 1;                         // interleaved pair split
    const int g = h >> 1;
    const int qbase = jq * 128;
    const int tid = threadIdx.x;                  // 0..511
    const int w = tid >> 6, lane = tid & 63, quad = lane >> 4, lr = lane & 15;
    const int t0 = qbase + w * 16;
    const int myq = b & 7;                        // arrival counter lane

    const short* Qb = (const short*)Qr + ((size_t)h * T_ + t0) * 256;
    const short* Kg = Kp + (size_t)g * NT_ * 8192;
    const short* Vg = Vp + (size_t)g * NT_ * 8192;

    short8 aq[8];
#pragma unroll
    for (int kk = 0; kk < 8; ++kk)
        aq[kk] = *(const short8*)(&Qb[(size_t)lr * 256 + kk * 32 + quad * 8]);

    floatx4 o[16] = {};
    floatx4 lacc = {0.f, 0.f, 0.f, 0.f};          // softmax denom via MFMA-ones
    float mrow[4] = {-3e38f, -3e38f, -3e38f, -3e38f};
    const float c = SCALE_ * LOG2E_;
    short* pw = &Pls[w][0];
    const short oneb = (short)0x3F80;             // bf16(1.0)
    const short8 ones8 = {oneb, oneb, oneb, oneb, oneb, oneb, oneb, oneb};

    const int nf_w = (PREV_ + t0) >> 5;                 // wave's last visible tile
    const int nf_b = (PREV_ + qbase + 127) >> 5;        // block's last useful tile

    // stage pair {ta, ta+1} into buffer buf: 32 K-chunks + 32 V-chunks of 1KB,
    // 8 waves x 4 each, fully contiguous global reads.
#define STAGE_PAIR(buf, ta_) do {                                              \
        for (int p_ = 0; p_ < 4; ++p_) {                                       \
            int q_ = w * 4 + p_, tt_ = q_ >> 4, cc_ = q_ & 15;                 \
            gld_lds(Kg + (size_t)((ta_) + tt_) * 8192 + (cc_ * 64 + lane) * 8, \
                    &Ks[buf][tt_][cc_ * 512]);                                 \
            gld_lds(Vg + (size_t)((ta_) + tt_) * 8192 + (cc_ * 64 + lane) * 8, \
                    &Vs[buf][tt_][cc_ * 512]);                                 \
        }                                                                      \
    } while (0)

    STAGE_PAIR(0, 2 * ns);
    int cur = 0;
    unsigned nbar = 0;
    for (int j = 0; j < NJ_; ++j) {
        if (j > 0 && (j & 3) == 0) { ++nbar; gbar(bar, myq, 256u * nbar); }
        else __syncthreads();       // vmcnt(0)+barrier: buffers[cur] staged & visible
        {
            const int nta = 4 * (j + 1) + 2 * ns;
            if (j + 1 < NJ_ && nta <= nf_b) STAGE_PAIR(cur ^ 1, nta);
        }
        const int ta = 4 * j + 2 * ns, tb = ta + 1;

        if (ta <= nf_w) {
            const int s0a = ta * 32, s0b = tb * 32;
            floatx4 sc[2][2];
            __builtin_amdgcn_s_setprio(1);
#pragma unroll
            for (int st = 0; st < 2; ++st) {
                const short* Kb = &Ks[cur][st][0];
#pragma unroll
                for (int half = 0; half < 2; ++half) {
                    floatx4 accs = {0.f, 0.f, 0.f, 0.f};
#pragma unroll
                    for (int kk = 0; kk < 8; ++kk) {
                        short8 bk = *(const short8*)&Kb[((kk * 2 + half) * 64 + ((quad * 16 + lr) ^ kk)) * 8];
                        accs = __builtin_amdgcn_mfma_f32_16x16x32_bf16(aq[kk], bk, accs, 0, 0, 0);
                    }
                    sc[st][half] = accs;
                }
            }
            __builtin_amdgcn_s_setprio(0);
            float mnew[4];
#pragma unroll
            for (int r = 0; r < 4; ++r) {
                float v00 = sc[0][0][r] * c, v01 = sc[0][1][r] * c;
                float v10 = sc[1][0][r] * c, v11 = sc[1][1][r] * c;
                const int limit = PREV_ + t0 + quad * 4 + r;
                if (ta >= nf_w) {
                    if (s0a + lr > limit)       v00 = -3e38f;
                    if (s0a + 16 + lr > limit)  v01 = -3e38f;
                }
                if (tb >= nf_w) {
                    if (s0b + lr > limit)       v10 = -3e38f;
                    if (s0b + 16 + lr > limit)  v11 = -3e38f;
                }
                sc[0][0][r] = v00; sc[0][1][r] = v01;
                sc[1][0][r] = v10; sc[1][1][r] = v11;
                float mx = fmaxf(fmaxf(v00, v01), fmaxf(v10, v11));
                mx = fmaxf(mx, __shfl_xor(mx, 1));
                mx = fmaxf(mx, __shfl_xor(mx, 2));
                mx = fmaxf(mx, __shfl_xor(mx, 4));
                mx = fmaxf(mx, __shfl_xor(mx, 8));
                mnew[r] = fmaxf(mrow[r], mx);
            }
            float alpha[4];
#pragma unroll
            for (int r = 0; r < 4; ++r) { alpha[r] = exp2f(mrow[r] - mnew[r]); mrow[r] = mnew[r]; }
#pragma unroll
            for (int r = 0; r < 4; ++r) {
                sc[0][0][r] = exp2f(sc[0][0][r] - mnew[r]);
                sc[0][1][r] = exp2f(sc[0][1][r] - mnew[r]);
                sc[1][0][r] = exp2f(sc[1][0][r] - mnew[r]);
                sc[1][1][r] = exp2f(sc[1][1][r] - mnew[r]);
            }
            bool need = (alpha[0] < 1.f) | (alpha[1] < 1.f) | (alpha[2] < 1.f) | (alpha[3] < 1.f);
            if (__any(need)) {
#pragma unroll
                for (int ni = 0; ni < 16; ++ni)
#pragma unroll
                    for (int r = 0; r < 4; ++r) o[ni][r] *= alpha[r];
#pragma unroll
                for (int r = 0; r < 4; ++r) lacc[r] *= alpha[r];
            }
            // P: D-layout -> packed A-layout in LDS (wave-local; lgkmcnt only)
#pragma unroll
            for (int st = 0; st < 2; ++st)
#pragma unroll
                for (int half = 0; half < 2; ++half)
#pragma unroll
                    for (int r = 0; r < 4; ++r) {
                        int koff2 = half * 16 + lr;
                        pw[st * 512 + ((koff2 >> 3) * 16 + quad * 4 + r) * 8 + (koff2 & 7)] = bfbits(sc[st][half][r]);
                    }
            __asm__ volatile("s_waitcnt lgkmcnt(0)" ::: "memory");
            short8 ap0 = *(const short8*)&pw[(quad * 16 + lr) * 8];
            short8 ap1 = *(const short8*)&pw[512 + (quad * 16 + lr) * 8];
            __builtin_amdgcn_s_setprio(1);
            lacc = __builtin_amdgcn_mfma_f32_16x16x32_bf16(ap0, ones8, lacc, 0, 0, 0);
            lacc = __builtin_amdgcn_mfma_f32_16x16x32_bf16(ap1, ones8, lacc, 0, 0, 0);
#pragma unroll
            for (int ni = 0; ni < 16; ++ni) {
                const int vs = (ni * 64 + ((quad * 16 + lr) ^ (ni & 7))) * 8;
                short8 bv0 = *(const short8*)&Vs[cur][0][vs];
                o[ni] = __builtin_amdgcn_mfma_f32_16x16x32_bf16(ap0, bv0, o[ni], 0, 0, 0);
                short8 bv1 = *(const short8*)&Vs[cur][1][vs];
                o[ni] = __builtin_amdgcn_mfma_f32_16x16x32_bf16(ap1, bv1, o[ni], 0, 0, 0);
            }
            __builtin_amdgcn_s_setprio(0);
        }
        cur ^= 1;
    }
#undef STAGE_PAIR

    // partial epilogue: unnormalized o + (m, l); 512B contiguous per store
    const int tq = jq * 8 + w;
    const size_t pb16 = (((size_t)h * 128 + tq) * NS_ + ns) * 16;
    const size_t pb = pb16 * 256;
#pragma unroll
    for (int ni = 0; ni < 16; ++ni) {
        union { unsigned long long u; short s4[4]; } pk;
#pragma unroll
        for (int r = 0; r < 4; ++r) pk.s4[r] = bfbits(o[ni][r]);
        *(unsigned long long*)&Po[pb + (size_t)ni * 256 + lane * 4] = pk.u;
    }
    if (lr == 0)
#pragma unroll
        for (int r = 0; r < 4; ++r) {
            Pm[pb16 + quad * 4 + r] = mrow[r];
            Pl[pb16 + quad * 4 + r] = lacc[r];
        }
}

// ---------------- combine split-s partials -> ctx[T][H*256] bf16
__global__ __launch_bounds__(256) void attn_combine(const short* __restrict__ Po,
                                                    const float* __restrict__ Pm,
                                                    const float* __restrict__ Pl,
                                                    __hip_bfloat16* __restrict__ ctx) {
    const int h = blockIdx.x;
    const int tt = blockIdx.y;
    const int tid = threadIdx.x;
    __shared__ float wgt[NS_][16];
    const size_t b = ((size_t)h * 128 + tt) * NS_;
    if (tid < 16) {
        const int row = tid;
        float m[NS_], l[NS_];
        float M = -3e38f;
        for (int ns = 0; ns < NS_; ++ns) {
            m[ns] = Pm[(b + ns) * 16 + row];
            l[ns] = Pl[(b + ns) * 16 + row];
            M = fmaxf(M, m[ns]);
        }
        float denom = 0.f, wv[NS_];
        for (int ns = 0; ns < NS_; ++ns) {
            wv[ns] = exp2f(m[ns] - M);
            denom += wv[ns] * l[ns];
        }
        float rd = 1.f / denom;
        for (int ns = 0; ns < NS_; ++ns) wgt[ns][row] = wv[ns] * rd;
    }
    __syncthreads();
    const int d = tid;
    const int ni = d >> 4, dl = d & 15;
    for (int row = 0; row < 16; ++row) {
        float acc = 0.f;
        // element (row, d): lane = (row>>2)*16 + (d&15), r = row&3, ni = d>>4
        const size_t ib = (size_t)ni * 256 + ((row >> 2) * 16 + dl) * 4 + (row & 3);
        for (int ns = 0; ns < NS_; ++ns)
            acc += wgt[ns][row] * b2f(Po[(b + ns) * 4096 + ib]);
        int t = tt * 16 + row;
        ctx[(size_t)t * (H_ * 256) + h * 256 + d] = __hip_bfloat16(acc);
    }
}

extern "C" void kernel_launch(void* const* d_in, const int* in_sizes, int n_in,
                              void* d_out, int out_size, void* d_ws, size_t ws_size,
                              hipStream_t stream) {
    const float* x       = (const float*)d_in[0];
    const float* Wq      = (const float*)d_in[1];
    const float* Wk      = (const float*)d_in[2];
    const float* Wv      = (const float*)d_in[3];
    const float* Wo      = (const float*)d_in[4];
    const float* q_scale = (const float*)d_in[5];
    const float* k_scale = (const float*)d_in[6];
    const float* k_cache = (const float*)d_in[7];
    const float* v_cache = (const float*)d_in[8];
    const float* cosd    = (const float*)d_in[9];
    const float* sind    = (const float*)d_in[10];
    float* out = (float*)d_out;   // reference output dtype is float32

    char* p = (char*)d_ws;
    float* q_f32 = (float*)p;            p += (size_t)T_ * 2048 * 4;   // 16 MiB
    float* k_f32 = (float*)p;            p += (size_t)T_ * 1024 * 4;   //  8 MiB
    float* v_f32 = (float*)p;            p += (size_t)T_ * 1024 * 4;   //  8 MiB
    __hip_bfloat16* Qr = (__hip_bfloat16*)p;  p += (size_t)H_ * T_ * 256 * 2;
    short* Kp = (short*)p;               p += (size_t)KV_ * NT_ * 1024 * 8 * 2;  // 12 MiB packed K tiles
    short* Vp = (short*)p;               p += (size_t)KV_ * NT_ * 1024 * 8 * 2;  // 12 MiB packed V tiles
    __hip_bfloat16* ctx = (__hip_bfloat16*)p; p += (size_t)T_ * 2048 * 2;
    float* Pm = (float*)p;               p += (size_t)H_ * 128 * NS_ * 16 * 4;
    float* Pl = (float*)p;               p += (size_t)H_ * 128 * NS_ * 16 * 4;
    unsigned* bar = (unsigned*)p;        p += 8 * 32 * sizeof(unsigned);
    // partial O aliases the (dead-by-then) q/k/v fp32 staging: 32 MiB region
    short* Po = (short*)d_ws;            // 8*128*2*16*256*2B = 16.8 MiB

    // fused QKV projection (fp32 out for norm precision)
    gemm_qkv<<<dim3(32, 16), 256, 0, stream>>>(x, Wq, Wk, Wv, q_f32, k_f32, v_f32);

    // norm + rope
    norm_rope_q<<<T_ * H_, 256, 0, stream>>>(q_f32, q_scale, cosd, sind, Qr);
    norm_rope_k<<<T_ * KV_, 256, 0, stream>>>(k_f32, k_scale, cosd, sind, Kp);

    // cache merge into packed tile layouts
    merge_k<<<dim3(PREV_ / 32, KV_), 256, 0, stream>>>(k_cache, Kp);
    transpose_v<<<dim3(SEFF_ / 64, HD_ / 64, KV_), 256, 0, stream>>>(v_cache, v_f32, Vp);

    // attention (flash v11: KVBLK=64, interleaved balanced split) + combine
    init_bar<<<1, 256, 0, stream>>>(bar);
    attn<<<dim3(256), 512, 0, stream>>>(Qr, Kp, Vp, Po, Pm, Pl, bar);
    attn_combine<<<dim3(H_, 128), 256, 0, stream>>>(Po, Pm, Pl, ctx);

    // output projection — fp32 output buffer
    gemm_wo<<<dim3(20, 32), 256, 0, stream>>>(ctx, Wo, out);
}